// Round 3
// baseline (429.622 us; speedup 1.0000x reference)
//
#include <hip/hip_runtime.h>

// GetCostVolume: out shape (B=4, 2C=64, D=48, H=64, W=128) fp32
//   c <  32: out[b,c,d,h,w] = (w>=d) ? x[b,c,h,w]      : 0
//   c >= 32: out[b,c,d,h,w] = (w>=d) ? y[b,c-32,h,w-d] : 0
//
// Round 4 (Round-2 fix: __builtin_nontemporal_store needs a NATIVE vector
// type, not HIP's float4 class -> store via ext_vector_type(4) float).
// Flat mapping — one thread per output float4, linear store front.
//   The 388us kernel walked d in-thread (48 stores @ 32KB stride per wave),
//   scattering 4KB chunks over the whole 402MB buffer at every instant
//   (~3 TB/s write). fillBufferAligned proves 6.2 TB/s on this buffer with
//   a linear front; this version reproduces that pattern.
//   Flat float4 index: o = (((b*64+cc)*48 + d)*64 + h)*32 + w4
//   A 256-thread block covers one (b,cc,d) and 8 h-rows -> d, cc, b are
//   block-uniform (SALU); branch cc<32 is uniform; masks compare vs scalar d.
//   y-half: aligned float4 load + chained __shfl_up window (s=d>>2, r=d&3);
//   clamped-shuffle lanes coincide exactly with masked (w<d) lanes.
//   Inputs are 8MB total -> 48x re-reads are L2/L3 hits, not HBM traffic.

typedef float f4_native __attribute__((ext_vector_type(4)));

__global__ __launch_bounds__(256) void cost_volume_kernel(
    const float* __restrict__ x, const float* __restrict__ y,
    f4_native* __restrict__ out)
{
    const int t    = threadIdx.x;
    const int w4   = t & 31;        // float4 index within row
    const int w0   = w4 << 2;
    const int hsub = t >> 5;        // 0..7

    const int g = blockIdx.x;       // 0..98303, one 16KB output chunk each
    const int h = ((g & 7) << 3) + hsub;
    int q = g >> 3;                 // (b*64+cc)*48 + d   (block-uniform)
    const int d = q % 48;
    q = q / 48;                     // b*64 + cc
    const int cc = q & 63;
    const int b  = q >> 6;

    float4 v;
    if (cc < 32) {
        v = *(const float4*)(x + (((b * 32 + cc) * 64 + h) << 7) + w0);
    } else {
        const float4 cur =
            *(const float4*)(y + (((b * 32 + (cc - 32)) * 64 + h) << 7) + w0);
        const int s = d >> 2;       // whole-float4 shift (uniform)
        const int r = d & 3;        // intra-float4 shift (uniform)
        float4 c2, p2;
        c2.x = __shfl_up(cur.x, s, 32);
        c2.y = __shfl_up(cur.y, s, 32);
        c2.z = __shfl_up(cur.z, s, 32);
        c2.w = __shfl_up(cur.w, s, 32);
        p2.x = __shfl_up(cur.x, s + 1, 32);
        p2.y = __shfl_up(cur.y, s + 1, 32);
        p2.z = __shfl_up(cur.z, s + 1, 32);
        p2.w = __shfl_up(cur.w, s + 1, 32);
        // element k: (k>=r) ? c2[k-r] : p2[4+k-r]
        switch (r) {
            case 0:  v = c2; break;
            case 1:  v = make_float4(p2.w, c2.x, c2.y, c2.z); break;
            case 2:  v = make_float4(p2.z, p2.w, c2.x, c2.y); break;
            default: v = make_float4(p2.y, p2.z, p2.w, c2.x); break;
        }
    }
    // mask w >= d (d is scalar)
    v.x = (w0 + 0 >= d) ? v.x : 0.0f;
    v.y = (w0 + 1 >= d) ? v.y : 0.0f;
    v.z = (w0 + 2 >= d) ? v.z : 0.0f;
    v.w = (w0 + 3 >= d) ? v.w : 0.0f;

    f4_native vn;
    vn.x = v.x; vn.y = v.y; vn.z = v.z; vn.w = v.w;
    __builtin_nontemporal_store(vn, &out[g * 256 + t]);
}

extern "C" void kernel_launch(void* const* d_in, const int* in_sizes, int n_in,
                              void* d_out, int out_size, void* d_ws, size_t ws_size,
                              hipStream_t stream) {
    const float* x = (const float*)d_in[0];
    const float* y = (const float*)d_in[1];
    f4_native* out = (f4_native*)d_out;

    const int block = 256;
    const int grid  = 98304;   // one block per 256-float4 output chunk
    cost_volume_kernel<<<grid, block, 0, stream>>>(x, y, out);
}

// Round 4
// 401.286 us; speedup vs baseline: 1.0706x; 1.0706x over previous
//
#include <hip/hip_runtime.h>

// GetCostVolume: out shape (B=4, 2C=64, D=48, H=64, W=128) fp32
//   c <  32: out[b,c,d,h,w] = (w>=d) ? x[b,c,h,w]      : 0
//   c >= 32: out[b,c,d,h,w] = (w>=d) ? y[b,c-32,h,w-d] : 0
//
// Round 5: blocked-linear store front.
//   R0 kernel (388us): 2048 WGs, 48 stores/thread at 32KB stride -> ~98K live
//     scattered store streams -> ~3.1 TB/s writes.
//   R4 kernel (430us): 98304 WGs, 1 store/thread -> WG-dispatch-rate-bound
//     (~4cy/WG ~= 164us) + nt stores bypass L2 write-combining.
//   This round: 3072 WGs (4 x 64 x 12), one per (b, cc, d-quad). Output layout
//   makes the d-range contiguous: each block writes ONE 128KB linear region.
//   Per thread: preload 8 h-rows of input (8 float4), then 32 masked stores.
//   y-half: shift s = d>>2 = dg is BLOCK-UNIFORM -> c2 = shfl_up(yv, dg),
//   p2 = shfl_up(yv, dg+1) once per h-row; the 4 d-stores are register
//   rotation (r = d&3) + mask. Clamped-shuffle lanes (w4 <= dg) have
//   w < 4*dg <= d -> masked to 0 anyway (same verified algebra as R0).
//   Normal (write-back) stores to match fillBufferAligned's 6.2 TB/s path.

__global__ __launch_bounds__(256) void cost_volume_kernel(
    const float* __restrict__ x, const float* __restrict__ y,
    float4* __restrict__ out)
{
    const int t    = threadIdx.x;
    const int w4   = t & 31;        // float4 index within row
    const int w0   = w4 << 2;
    const int hsub = t >> 5;        // 0..7

    const int bid = blockIdx.x;     // 0..3071, monotone in output address
    const int dg  = bid % 12;       // d-quad: d = 4*dg + j, j = 0..3
    const int q   = bid / 12;
    const int cc  = q & 63;
    const int b   = q >> 6;
    const int d0  = dg << 2;

    // output base (float4 units): (((b*64+cc)*48 + d0)*64 + h)*32 + w4
    //   = slice + d*2048 + ho*256 + t
    float4* outp = out + (((b * 64 + cc) * 48 + d0) * 2048 + t);

    float4 c2[8], p2[8];            // x-half uses only c2[]
    if (cc < 32) {
        const float* xp = x + (((b * 32 + cc) * 64 + hsub) << 7) + w0;
#pragma unroll
        for (int ho = 0; ho < 8; ++ho)
            c2[ho] = *(const float4*)(xp + (ho << 10));  // h += 8 rows
#pragma unroll
        for (int j = 0; j < 4; ++j) {
            const int d = d0 + j;
#pragma unroll
            for (int ho = 0; ho < 8; ++ho) {
                float4 v = c2[ho];
                v.x = (w0 + 0 >= d) ? v.x : 0.0f;
                v.y = (w0 + 1 >= d) ? v.y : 0.0f;
                v.z = (w0 + 2 >= d) ? v.z : 0.0f;
                v.w = (w0 + 3 >= d) ? v.w : 0.0f;
                outp[j * 2048 + ho * 256] = v;
            }
        }
    } else {
        const float* yp = y + (((b * 32 + (cc - 32)) * 64 + hsub) << 7) + w0;
#pragma unroll
        for (int ho = 0; ho < 8; ++ho) {
            const float4 yv = *(const float4*)(yp + (ho << 10));
            c2[ho].x = __shfl_up(yv.x, dg, 32);
            c2[ho].y = __shfl_up(yv.y, dg, 32);
            c2[ho].z = __shfl_up(yv.z, dg, 32);
            c2[ho].w = __shfl_up(yv.w, dg, 32);
            p2[ho].x = __shfl_up(yv.x, dg + 1, 32);
            p2[ho].y = __shfl_up(yv.y, dg + 1, 32);
            p2[ho].z = __shfl_up(yv.z, dg + 1, 32);
            p2[ho].w = __shfl_up(yv.w, dg + 1, 32);
        }
#pragma unroll
        for (int j = 0; j < 4; ++j) {
            const int d = d0 + j;
#pragma unroll
            for (int ho = 0; ho < 8; ++ho) {
                // element k: (k>=j) ? c2[k-j] : p2[4+k-j]
                float4 v;
                switch (j) {
                    case 0:  v = c2[ho]; break;
                    case 1:  v = make_float4(p2[ho].w, c2[ho].x, c2[ho].y, c2[ho].z); break;
                    case 2:  v = make_float4(p2[ho].z, p2[ho].w, c2[ho].x, c2[ho].y); break;
                    default: v = make_float4(p2[ho].y, p2[ho].z, p2[ho].w, c2[ho].x); break;
                }
                v.x = (w0 + 0 >= d) ? v.x : 0.0f;
                v.y = (w0 + 1 >= d) ? v.y : 0.0f;
                v.z = (w0 + 2 >= d) ? v.z : 0.0f;
                v.w = (w0 + 3 >= d) ? v.w : 0.0f;
                outp[j * 2048 + ho * 256] = v;
            }
        }
    }
}

extern "C" void kernel_launch(void* const* d_in, const int* in_sizes, int n_in,
                              void* d_out, int out_size, void* d_ws, size_t ws_size,
                              hipStream_t stream) {
    const float* x = (const float*)d_in[0];
    const float* y = (const float*)d_in[1];
    float4* out = (float4*)d_out;

    const int block = 256;
    const int grid  = 4 * 64 * 12;   // 3072 blocks, one 128KB output region each
    cost_volume_kernel<<<grid, block, 0, stream>>>(x, y, out);
}